// Round 4
// baseline (813.050 us; speedup 1.0000x reference)
//
#include <hip/hip_runtime.h>
#include <stdint.h>

// VQ argmin, bit-replicating numpy fp32 reference (see R2).
// R10: packed fp32. R6/R8/R9 all pin at 237-251us with VALUBusy ~62%
// regardless of wave count or LDS/VMEM mix -> the kernel is VALU-issue
// bound (147us of VALU-busy vs 109us pure-FMA floor). MI355X fp32 peak
// (157.3 TF) is 2x the plain v_fma_f32 rate -> reachable only via
// v_pk_fma_f32 (2 independent IEEE fp32 FMAs/instr). Pack code-pairs into
// float2 accumulators (__builtin_elementwise_fma -> llvm.fma.v2f32 ->
// v_pk_fma_f32): FMA instr count halves, issue floor 109 -> 55us. Each
// packed lane keeps its own ascending-k fma chain -> BIT-EXACT vs R2-R9
// (absmax must stay 1.907349e-06). Also 2x-unroll the phase loop so LDS
// buffer bases are static -> all 64 reads/phase use [base + imm-offset],
// killing per-phase address/select VALU overhead.
// B=16 D=256 H=W=32 -> n=16384 pixels; K=2048 codes.

#define D_    256
#define K_    2048
#define HW_   1024
#define MT    64      // pixels per block
#define NT    256     // codes per acc chunk
#define KT    16      // dims per phase
#define SPLIT 4
#define KS    (K_ / SPLIT)   // 512 codes per block
#define CST   256     // cs row stride (floats); 2-way banks on read = free
#define BUFSZ (KT * MT + KT * CST)   // 5120 floats per buffer
#define NPH   ((KS / NT) * KT)       // 32 phases
#define NPIX  16384

typedef float v2f __attribute__((ext_vector_type(2)));

// global -> LDS direct DMA, 16 B per lane, wave-uniform LDS base (CK-style casts)
__device__ __forceinline__ void gload16(const float* g, float* l) {
    auto* gp = reinterpret_cast<const __attribute__((address_space(1))) uint32_t*>(
        reinterpret_cast<uintptr_t>(g));
    auto* lp = reinterpret_cast<__attribute__((address_space(3))) uint32_t*>(
        reinterpret_cast<uintptr_t>(l));
    __builtin_amdgcn_global_load_lds(gp, lp, 16, 0, 0);
}

// numpy pairwise combine of 8 accumulators
__device__ __forceinline__ float pw8(const float r[8]) {
    float t01 = __fadd_rn(r[0], r[1]);
    float t23 = __fadd_rn(r[2], r[3]);
    float L   = __fadd_rn(t01, t23);
    float t45 = __fadd_rn(r[4], r[5]);
    float t67 = __fadd_rn(r[6], r[7]);
    float R   = __fadd_rn(t45, t67);
    return __fadd_rn(L, R);
}

// prep: blocks [0,128) transpose cb->ct; [128,136) Bn; [136,200) An
__global__ __launch_bounds__(256) void prep_k(const float* __restrict__ z,
                                              const float* __restrict__ cb,
                                              float* __restrict__ ct,
                                              float* __restrict__ An,
                                              float* __restrict__ Bn) {
    __shared__ float t[64][65];
    int tid = threadIdx.x;
    int bx  = blockIdx.x;
    if (bx < 128) {
        int k0 = (bx & 31) << 6;
        int d0 = (bx >> 5) << 6;
        #pragma unroll
        for (int it = 0; it < 4; ++it) {
            int u  = (it << 8) + tid;
            int kk = u >> 4;
            int dd = (u & 15) << 2;
            float4 v = *reinterpret_cast<const float4*>(
                cb + (size_t)(k0 + kk) * D_ + d0 + dd);
            t[kk][dd + 0] = v.x; t[kk][dd + 1] = v.y;
            t[kk][dd + 2] = v.z; t[kk][dd + 3] = v.w;
        }
        __syncthreads();
        #pragma unroll
        for (int it = 0; it < 4; ++it) {
            int u  = (it << 8) + tid;
            int dd = u >> 4;
            int kk = (u & 15) << 2;
            float4 o;
            o.x = t[kk + 0][dd]; o.y = t[kk + 1][dd];
            o.z = t[kk + 2][dd]; o.w = t[kk + 3][dd];
            *reinterpret_cast<float4*>(ct + (size_t)(d0 + dd) * K_ + k0 + kk) = o;
        }
    } else if (bx < 136) {
        int row = (bx - 128) * 256 + tid;
        const float4* p = reinterpret_cast<const float4*>(cb + (size_t)row * D_);
        float rA[8], rB[8];
        #pragma unroll
        for (int j = 0; j < 8; ++j) { rA[j] = 0.f; rB[j] = 0.f; }
        #pragma unroll
        for (int q = 0; q < 64; ++q) {
            float4 v = p[q];
            float pv[4] = {__fmul_rn(v.x, v.x), __fmul_rn(v.y, v.y),
                           __fmul_rn(v.z, v.z), __fmul_rn(v.w, v.w)};
            if (q < 32) {
                #pragma unroll
                for (int l = 0; l < 4; ++l)
                    rA[(4 * q + l) & 7] = __fadd_rn(rA[(4 * q + l) & 7], pv[l]);
            } else {
                #pragma unroll
                for (int l = 0; l < 4; ++l)
                    rB[(4 * q + l) & 7] = __fadd_rn(rB[(4 * q + l) & 7], pv[l]);
            }
        }
        Bn[row] = __fadd_rn(pw8(rA), pw8(rB));
    } else {
        int blk = bx - 136;                  // [0,64): 256 pixels each
        int b   = blk >> 2;
        int hw0 = (blk & 3) << 8;
        const float* zb = z + (size_t)b * (D_ * HW_) + hw0 + tid;
        float rA[8], rB[8];
        #pragma unroll
        for (int j = 0; j < 8; ++j) { rA[j] = 0.f; rB[j] = 0.f; }
        #pragma unroll 8
        for (int d = 0; d < 128; ++d) {      // coalesced: consecutive threads
            float v = zb[(size_t)d * HW_];
            rA[d & 7] = __fadd_rn(rA[d & 7], __fmul_rn(v, v));
        }
        #pragma unroll 8
        for (int d = 128; d < 256; ++d) {
            float v = zb[(size_t)d * HW_];
            rB[d & 7] = __fadd_rn(rB[d & 7], __fmul_rn(v, v));
        }
        An[(size_t)b * HW_ + hw0 + tid] = __fadd_rn(pw8(rA), pw8(rB));
    }
}

// one phase of FMA work from a statically-based LDS buffer pair
__device__ __forceinline__ void compute_phase(const float* zb_, const float* cb_,
                                              int tm, int tn, v2f acc[8][4]) {
    #pragma unroll
    for (int d = 0; d < KT; ++d) {
        const float* zr = zb_ + d * MT + (tm << 3);
        float4 a0 = *reinterpret_cast<const float4*>(zr);
        float4 a1 = *reinterpret_cast<const float4*>(zr + 4);
        const float* cr = cb_ + d * CST + (tn << 3);
        float4 b0 = *reinterpret_cast<const float4*>(cr);
        float4 b1 = *reinterpret_cast<const float4*>(cr + 4);
        v2f bp0 = {b0.x, b0.y}, bp1 = {b0.z, b0.w};
        v2f bp2 = {b1.x, b1.y}, bp3 = {b1.z, b1.w};
        float az[8] = {a0.x, a0.y, a0.z, a0.w, a1.x, a1.y, a1.z, a1.w};
        #pragma unroll
        for (int i = 0; i < 8; ++i) {
            v2f ai = {az[i], az[i]};
            acc[i][0] = __builtin_elementwise_fma(ai, bp0, acc[i][0]);
            acc[i][1] = __builtin_elementwise_fma(ai, bp1, acc[i][1]);
            acc[i][2] = __builtin_elementwise_fma(ai, bp2, acc[i][2]);
            acc[i][3] = __builtin_elementwise_fma(ai, bp3, acc[i][3]);
        }
    }
}

// main GEMM+argmin: LDS double-buffered via global_load_lds DMA, pk_fma math
__global__ __launch_bounds__(256, 2) void vq_k(const float* __restrict__ z,
                                               const float* __restrict__ ct,
                                               const float* __restrict__ An,
                                               const float* __restrict__ Bn,
                                               float* __restrict__ pscore,
                                               int* __restrict__ pidx) {
    __shared__ float smem[2 * BUFSZ];            // 40960 B
    float* rs = smem;                            // aliased for reduce
    int*   ri = (int*)(smem + MT * 33);

    const int tid  = threadIdx.x;
    const int lane = tid & 63;
    const int w    = tid >> 6;                   // wave id [0,4)
    const int tn   = (tid & 7) | (w << 3);       // [0,32) code-group
    const int tm   = (tid >> 3) & 7;             // [0,8)  pixel-group
    const int blk  = blockIdx.x;
    const int p    = blk / SPLIT;                // pixel-block [0,256)
    const int s    = blk % SPLIT;                // K-split slice
    const int b      = p >> 4;
    const int hwbase = (p & 15) << 6;
    const float* zbase = z + (size_t)b * (D_ * HW_) + hwbase;
    const float* ctS   = ct + s * KS;

    // per-lane DMA source bases (z: lane covers row 4w+(lane>>4), col (lane&15)*4)
    const float* zsrc = zbase + (size_t)((w << 2) + (lane >> 4)) * HW_
                              + ((lane & 15) << 2);

    float* zb0 = smem;
    float* cb0 = smem + KT * MT;
    float* zb1 = smem + BUFSZ;
    float* cb1 = zb1 + KT * MT;

    float bs[8]; int bi[8];
    #pragma unroll
    for (int i = 0; i < 8; ++i) { bs[i] = 1e30f; bi[i] = 0; }
    v2f acc[8][4];
    #pragma unroll
    for (int i = 0; i < 8; ++i)
        #pragma unroll
        for (int j = 0; j < 4; ++j) acc[i][j] = (v2f){0.f, 0.f};

    // stage phase ph into (zd_, cd_): 1 z-DMA + 4 cs-row-DMAs per wave
    #define STAGE(ph, zd_, cd_)                                               \
        do {                                                                  \
            int kc_ = (ph) & 15, nc_ = (ph) >> 4;                             \
            gload16(zsrc + (size_t)kc_ * (KT * HW_), (zd_) + (w << 2) * MT);  \
            _Pragma("unroll")                                                 \
            for (int r = 0; r < 4; ++r) {                                     \
                int row = (w << 2) + r;                                       \
                gload16(ctS + (size_t)((kc_ << 4) + row) * K_ + nc_ * NT      \
                            + (lane << 2),                                    \
                        (cd_) + row * CST);                                   \
            }                                                                 \
        } while (0)

    // argmin flush for chunk nc (acc[i][j>>1][j&1] == old acc[i][j], bit-exact)
    #define FLUSH(nc_)                                                        \
        do {                                                                  \
            int nc = (nc_);                                                   \
            _Pragma("unroll")                                                 \
            for (int j = 0; j < 8; ++j) {                                     \
                int ng = s * KS + nc * NT + (tn << 3) + j;                    \
                float bn = Bn[ng];                                            \
                _Pragma("unroll")                                             \
                for (int i = 0; i < 8; ++i) {                                 \
                    float an = An[(size_t)b * HW_ + hwbase + (tm << 3) + i];  \
                    float sc = __fsub_rn(__fadd_rn(an, bn),                   \
                                         __fmul_rn(2.0f, acc[i][j >> 1][j & 1])); \
                    if (sc < bs[i]) { bs[i] = sc; bi[i] = ng; }               \
                }                                                             \
            }                                                                 \
            _Pragma("unroll")                                                 \
            for (int i = 0; i < 8; ++i) {                                     \
                acc[i][0] = (v2f){0.f, 0.f}; acc[i][1] = (v2f){0.f, 0.f};     \
                acc[i][2] = (v2f){0.f, 0.f}; acc[i][3] = (v2f){0.f, 0.f};     \
            }                                                                 \
        } while (0)

    STAGE(0, zb0, cb0);

    for (int ph = 0; ph < NPH; ph += 2) {
        __syncthreads();          // drains buf0 DMA (issued 1 half-phase ago)
        if (ph + 1 < NPH) STAGE(ph + 1, zb1, cb1);
        compute_phase(zb0, cb0, tm, tn, acc);   // ph even: never a flush point
        __syncthreads();          // drains buf1 DMA
        if (ph + 2 < NPH) STAGE(ph + 2, zb0, cb0);
        compute_phase(zb1, cb1, tm, tn, acc);
        if (((ph + 1) & 15) == 15) FLUSH((ph + 1) >> 4);
    }
    #undef STAGE
    #undef FLUSH

    __syncthreads();   // protect smem before aliasing
    #pragma unroll
    for (int i = 0; i < 8; ++i) {
        int m = (tm << 3) + i;
        rs[m * 33 + tn] = bs[i];
        ri[m * 33 + tn] = bi[i];
    }
    __syncthreads();
    if (tid < MT) {
        int   m    = tid;
        float best = rs[m * 33];
        int   bidx = ri[m * 33];
        for (int t = 1; t < 32; ++t) {
            float sv = rs[m * 33 + t];
            int   ix = ri[m * 33 + t];
            if (sv < best || (sv == best && ix < bidx)) { best = sv; bidx = ix; }
        }
        int g = b * HW_ + hwbase + m;
        pscore[s * NPIX + g] = best;
        pidx[s * NPIX + g]   = bidx;
    }
}

// merge SPLIT partials (first-min tiebreak) + gather output
__global__ __launch_bounds__(256) void fin_k(const float* __restrict__ cb,
                                             const float* __restrict__ pscore,
                                             const int* __restrict__ pidx,
                                             float* __restrict__ out) {
    __shared__ int idxs[MT];
    int tid = threadIdx.x;
    int p   = blockIdx.x;               // [0,256)
    int b      = p >> 4;
    int hwbase = (p & 15) << 6;
    if (tid < MT) {
        int g = b * HW_ + hwbase + tid;
        float best = pscore[g];
        int   bidx = pidx[g];
        #pragma unroll
        for (int s = 1; s < SPLIT; ++s) {
            float sv = pscore[s * NPIX + g];
            int   ix = pidx[s * NPIX + g];
            if (sv < best || (sv == best && ix < bidx)) { best = sv; bidx = ix; }
        }
        idxs[tid] = bidx;
    }
    __syncthreads();
    float* obase = out + (size_t)b * (D_ * HW_) + hwbase;
    #pragma unroll
    for (int it = 0; it < 16; ++it) {
        int u  = (it << 8) + tid;
        int dd = u >> 4;                // [0,256)
        int m4 = u & 15;
        int i0 = idxs[(m4 << 2) + 0];
        int i1 = idxs[(m4 << 2) + 1];
        int i2 = idxs[(m4 << 2) + 2];
        int i3 = idxs[(m4 << 2) + 3];
        float4 o;
        o.x = cb[(size_t)i0 * D_ + dd];
        o.y = cb[(size_t)i1 * D_ + dd];
        o.z = cb[(size_t)i2 * D_ + dd];
        o.w = cb[(size_t)i3 * D_ + dd];
        *reinterpret_cast<float4*>(obase + (size_t)dd * HW_ + (m4 << 2)) = o;
    }
}

extern "C" void kernel_launch(void* const* d_in, const int* in_sizes, int n_in,
                              void* d_out, int out_size, void* d_ws, size_t ws_size,
                              hipStream_t stream) {
    const float* z  = (const float*)d_in[0];   // 16*256*32*32
    const float* cb = (const float*)d_in[1];   // 2048*256
    float* pscore = (float*)d_ws;                       // 4*16384
    int*   pidx   = (int*)(pscore + SPLIT * NPIX);      // 4*16384
    float* An     = (float*)(pidx + SPLIT * NPIX);      // 16384
    float* Bn     = An + NPIX;                          // 2048
    float* ct     = Bn + K_;                            // 256*2048 (2 MB)
    float* out    = (float*)d_out;

    prep_k<<<dim3(200), dim3(256), 0, stream>>>(z, cb, ct, An, Bn);
    vq_k<<<dim3(256 * SPLIT), dim3(256), 0, stream>>>(z, ct, An, Bn, pscore, pidx);
    fin_k<<<dim3(256), dim3(256), 0, stream>>>(cb, pscore, pidx, out);
}

// Round 5
// 295.270 us; speedup vs baseline: 2.7536x; 2.7536x over previous
//
#include <hip/hip_runtime.h>
#include <stdint.h>

// VQ argmin, bit-replicating numpy fp32 reference (see R2).
// R11: packed fp32, take 2. R10 moved the FMA body into a helper taking
// `v2f acc[8][4]` as a parameter -> array-to-pointer decay -> alloca that
// SROA never removed -> accumulators in scratch (FETCH 1.1 GB, 735us).
// R11 keeps R8's exact proven structure (single loop, inline body, no
// helper, launch_bounds(256,2), SPLIT=4, z via LDS) and changes ONLY the
// accumulator: v2f acc[8][4] local, fully-static unrolled indexing, FMA via
// __builtin_elementwise_fma -> llvm.fma.v2f32 -> v_pk_fma_f32 (2 IEEE fp32
// FMAs/instr; MI355X fp32 peak 157.3TF = 2x plain v_fma rate). Each packed
// lane keeps its own ascending-k fma chain -> BIT-EXACT vs R2-R9 (absmax
// must stay 1.907349e-06). FMA instr/phase halves: issue floor 109 -> 55us.
// B=16 D=256 H=W=32 -> n=16384 pixels; K=2048 codes.

#define D_    256
#define K_    2048
#define HW_   1024
#define MT    64      // pixels per block
#define NT    256     // codes per acc chunk
#define KT    16      // dims per phase
#define SPLIT 4
#define KS    (K_ / SPLIT)   // 512 codes per block
#define CST   256     // cs row stride (floats); 2-way banks on read = free
#define BUFSZ (KT * MT + KT * CST)   // 5120 floats per buffer
#define NPH   ((KS / NT) * KT)       // 32 phases
#define NPIX  16384

typedef float v2f __attribute__((ext_vector_type(2)));

// global -> LDS direct DMA, 16 B per lane, wave-uniform LDS base (CK-style casts)
__device__ __forceinline__ void gload16(const float* g, float* l) {
    auto* gp = reinterpret_cast<const __attribute__((address_space(1))) uint32_t*>(
        reinterpret_cast<uintptr_t>(g));
    auto* lp = reinterpret_cast<__attribute__((address_space(3))) uint32_t*>(
        reinterpret_cast<uintptr_t>(l));
    __builtin_amdgcn_global_load_lds(gp, lp, 16, 0, 0);
}

// numpy pairwise combine of 8 accumulators
__device__ __forceinline__ float pw8(const float r[8]) {
    float t01 = __fadd_rn(r[0], r[1]);
    float t23 = __fadd_rn(r[2], r[3]);
    float L   = __fadd_rn(t01, t23);
    float t45 = __fadd_rn(r[4], r[5]);
    float t67 = __fadd_rn(r[6], r[7]);
    float R   = __fadd_rn(t45, t67);
    return __fadd_rn(L, R);
}

// prep: blocks [0,128) transpose cb->ct; [128,136) Bn; [136,200) An
__global__ __launch_bounds__(256) void prep_k(const float* __restrict__ z,
                                              const float* __restrict__ cb,
                                              float* __restrict__ ct,
                                              float* __restrict__ An,
                                              float* __restrict__ Bn) {
    __shared__ float t[64][65];
    int tid = threadIdx.x;
    int bx  = blockIdx.x;
    if (bx < 128) {
        int k0 = (bx & 31) << 6;
        int d0 = (bx >> 5) << 6;
        #pragma unroll
        for (int it = 0; it < 4; ++it) {
            int u  = (it << 8) + tid;
            int kk = u >> 4;
            int dd = (u & 15) << 2;
            float4 v = *reinterpret_cast<const float4*>(
                cb + (size_t)(k0 + kk) * D_ + d0 + dd);
            t[kk][dd + 0] = v.x; t[kk][dd + 1] = v.y;
            t[kk][dd + 2] = v.z; t[kk][dd + 3] = v.w;
        }
        __syncthreads();
        #pragma unroll
        for (int it = 0; it < 4; ++it) {
            int u  = (it << 8) + tid;
            int dd = u >> 4;
            int kk = (u & 15) << 2;
            float4 o;
            o.x = t[kk + 0][dd]; o.y = t[kk + 1][dd];
            o.z = t[kk + 2][dd]; o.w = t[kk + 3][dd];
            *reinterpret_cast<float4*>(ct + (size_t)(d0 + dd) * K_ + k0 + kk) = o;
        }
    } else if (bx < 136) {
        int row = (bx - 128) * 256 + tid;
        const float4* p = reinterpret_cast<const float4*>(cb + (size_t)row * D_);
        float rA[8], rB[8];
        #pragma unroll
        for (int j = 0; j < 8; ++j) { rA[j] = 0.f; rB[j] = 0.f; }
        #pragma unroll
        for (int q = 0; q < 64; ++q) {
            float4 v = p[q];
            float pv[4] = {__fmul_rn(v.x, v.x), __fmul_rn(v.y, v.y),
                           __fmul_rn(v.z, v.z), __fmul_rn(v.w, v.w)};
            if (q < 32) {
                #pragma unroll
                for (int l = 0; l < 4; ++l)
                    rA[(4 * q + l) & 7] = __fadd_rn(rA[(4 * q + l) & 7], pv[l]);
            } else {
                #pragma unroll
                for (int l = 0; l < 4; ++l)
                    rB[(4 * q + l) & 7] = __fadd_rn(rB[(4 * q + l) & 7], pv[l]);
            }
        }
        Bn[row] = __fadd_rn(pw8(rA), pw8(rB));
    } else {
        int blk = bx - 136;                  // [0,64): 256 pixels each
        int b   = blk >> 2;
        int hw0 = (blk & 3) << 8;
        const float* zb = z + (size_t)b * (D_ * HW_) + hw0 + tid;
        float rA[8], rB[8];
        #pragma unroll
        for (int j = 0; j < 8; ++j) { rA[j] = 0.f; rB[j] = 0.f; }
        #pragma unroll 8
        for (int d = 0; d < 128; ++d) {      // coalesced: consecutive threads
            float v = zb[(size_t)d * HW_];
            rA[d & 7] = __fadd_rn(rA[d & 7], __fmul_rn(v, v));
        }
        #pragma unroll 8
        for (int d = 128; d < 256; ++d) {
            float v = zb[(size_t)d * HW_];
            rB[d & 7] = __fadd_rn(rB[d & 7], __fmul_rn(v, v));
        }
        An[(size_t)b * HW_ + hw0 + tid] = __fadd_rn(pw8(rA), pw8(rB));
    }
}

// main GEMM+argmin: LDS double-buffered via global_load_lds DMA, pk_fma math
__global__ __launch_bounds__(256, 2) void vq_k(const float* __restrict__ z,
                                               const float* __restrict__ ct,
                                               const float* __restrict__ An,
                                               const float* __restrict__ Bn,
                                               float* __restrict__ pscore,
                                               int* __restrict__ pidx) {
    __shared__ float smem[2 * BUFSZ];            // 40960 B
    float* rs = smem;                            // aliased for reduce
    int*   ri = (int*)(smem + MT * 33);

    const int tid  = threadIdx.x;
    const int lane = tid & 63;
    const int w    = tid >> 6;                   // wave id [0,4)
    const int tn   = (tid & 7) | (w << 3);       // [0,32) code-group
    const int tm   = (tid >> 3) & 7;             // [0,8)  pixel-group
    const int blk  = blockIdx.x;
    const int p    = blk / SPLIT;                // pixel-block [0,256)
    const int s    = blk % SPLIT;                // K-split slice
    const int b      = p >> 4;
    const int hwbase = (p & 15) << 6;
    const float* zbase = z + (size_t)b * (D_ * HW_) + hwbase;
    const float* ctS   = ct + s * KS;

    // per-lane DMA source bases (z: lane covers row 4w+(lane>>4), col (lane&15)*4)
    const float* zsrc = zbase + (size_t)((w << 2) + (lane >> 4)) * HW_
                              + ((lane & 15) << 2);

    float bs[8]; int bi[8];
    #pragma unroll
    for (int i = 0; i < 8; ++i) { bs[i] = 1e30f; bi[i] = 0; }
    v2f acc[8][4];
    #pragma unroll
    for (int i = 0; i < 8; ++i)
        #pragma unroll
        for (int jp = 0; jp < 4; ++jp) acc[i][jp] = (v2f){0.f, 0.f};

    // stage phase ph into buf[ph&1]: 1 z-DMA + 4 cs-row-DMAs per wave
    #define STAGE(ph)                                                         \
        do {                                                                  \
            int buf_ = (ph) & 1, kc_ = (ph) & 15, nc_ = (ph) >> 4;            \
            float* zb_ = smem + buf_ * BUFSZ;                                 \
            float* cb_ = zb_ + KT * MT;                                       \
            gload16(zsrc + (size_t)kc_ * (KT * HW_), zb_ + (w << 2) * MT);    \
            _Pragma("unroll")                                                 \
            for (int r = 0; r < 4; ++r) {                                     \
                int row = (w << 2) + r;                                       \
                gload16(ctS + (size_t)((kc_ << 4) + row) * K_ + nc_ * NT      \
                            + (lane << 2),                                    \
                        cb_ + row * CST);                                     \
            }                                                                 \
        } while (0)

    STAGE(0);

    for (int ph = 0; ph < NPH; ++ph) {
        __syncthreads();          // drains phase-ph DMA (issued 1 phase ago)
        if (ph < NPH - 1) STAGE(ph + 1);  // into other buffer (safe: read at ph-1)
        const float* zb_ = smem + (ph & 1) * BUFSZ;
        const float* cb_ = zb_ + KT * MT;
        // ascending-k per-accumulator fma chains — bit-match sgemm
        #pragma unroll
        for (int d = 0; d < KT; ++d) {
            const float* zr = zb_ + d * MT + (tm << 3);
            float4 a0 = *reinterpret_cast<const float4*>(zr);
            float4 a1 = *reinterpret_cast<const float4*>(zr + 4);
            const float* cr = cb_ + d * CST + (tn << 3);
            float4 b0 = *reinterpret_cast<const float4*>(cr);
            float4 b1 = *reinterpret_cast<const float4*>(cr + 4);
            v2f bp0 = {b0.x, b0.y}, bp1 = {b0.z, b0.w};
            v2f bp2 = {b1.x, b1.y}, bp3 = {b1.z, b1.w};
            float az[8] = {a0.x, a0.y, a0.z, a0.w, a1.x, a1.y, a1.z, a1.w};
            #pragma unroll
            for (int i = 0; i < 8; ++i) {
                v2f ai = {az[i], az[i]};
                acc[i][0] = __builtin_elementwise_fma(ai, bp0, acc[i][0]);
                acc[i][1] = __builtin_elementwise_fma(ai, bp1, acc[i][1]);
                acc[i][2] = __builtin_elementwise_fma(ai, bp2, acc[i][2]);
                acc[i][3] = __builtin_elementwise_fma(ai, bp3, acc[i][3]);
            }
        }
        if ((ph & 15) == 15) {
            int nc = ph >> 4;
            #pragma unroll
            for (int j = 0; j < 8; ++j) {
                int ng = s * KS + nc * NT + (tn << 3) + j;
                float bn = Bn[ng];
                #pragma unroll
                for (int i = 0; i < 8; ++i) {
                    float an = An[(size_t)b * HW_ + hwbase + (tm << 3) + i];
                    float sc = __fsub_rn(__fadd_rn(an, bn),
                                         __fmul_rn(2.0f, acc[i][j >> 1][j & 1]));
                    if (sc < bs[i]) { bs[i] = sc; bi[i] = ng; }
                }
            }
            #pragma unroll
            for (int i = 0; i < 8; ++i) {
                acc[i][0] = (v2f){0.f, 0.f}; acc[i][1] = (v2f){0.f, 0.f};
                acc[i][2] = (v2f){0.f, 0.f}; acc[i][3] = (v2f){0.f, 0.f};
            }
        }
    }
    #undef STAGE

    __syncthreads();   // protect smem before aliasing
    #pragma unroll
    for (int i = 0; i < 8; ++i) {
        int m = (tm << 3) + i;
        rs[m * 33 + tn] = bs[i];
        ri[m * 33 + tn] = bi[i];
    }
    __syncthreads();
    if (tid < MT) {
        int   m    = tid;
        float best = rs[m * 33];
        int   bidx = ri[m * 33];
        for (int t = 1; t < 32; ++t) {
            float sv = rs[m * 33 + t];
            int   ix = ri[m * 33 + t];
            if (sv < best || (sv == best && ix < bidx)) { best = sv; bidx = ix; }
        }
        int g = b * HW_ + hwbase + m;
        pscore[s * NPIX + g] = best;
        pidx[s * NPIX + g]   = bidx;
    }
}

// merge SPLIT partials (first-min tiebreak) + gather output
__global__ __launch_bounds__(256) void fin_k(const float* __restrict__ cb,
                                             const float* __restrict__ pscore,
                                             const int* __restrict__ pidx,
                                             float* __restrict__ out) {
    __shared__ int idxs[MT];
    int tid = threadIdx.x;
    int p   = blockIdx.x;               // [0,256)
    int b      = p >> 4;
    int hwbase = (p & 15) << 6;
    if (tid < MT) {
        int g = b * HW_ + hwbase + tid;
        float best = pscore[g];
        int   bidx = pidx[g];
        #pragma unroll
        for (int s = 1; s < SPLIT; ++s) {
            float sv = pscore[s * NPIX + g];
            int   ix = pidx[s * NPIX + g];
            if (sv < best || (sv == best && ix < bidx)) { best = sv; bidx = ix; }
        }
        idxs[tid] = bidx;
    }
    __syncthreads();
    float* obase = out + (size_t)b * (D_ * HW_) + hwbase;
    #pragma unroll
    for (int it = 0; it < 16; ++it) {
        int u  = (it << 8) + tid;
        int dd = u >> 4;                // [0,256)
        int m4 = u & 15;
        int i0 = idxs[(m4 << 2) + 0];
        int i1 = idxs[(m4 << 2) + 1];
        int i2 = idxs[(m4 << 2) + 2];
        int i3 = idxs[(m4 << 2) + 3];
        float4 o;
        o.x = cb[(size_t)i0 * D_ + dd];
        o.y = cb[(size_t)i1 * D_ + dd];
        o.z = cb[(size_t)i2 * D_ + dd];
        o.w = cb[(size_t)i3 * D_ + dd];
        *reinterpret_cast<float4*>(obase + (size_t)dd * HW_ + (m4 << 2)) = o;
    }
}

extern "C" void kernel_launch(void* const* d_in, const int* in_sizes, int n_in,
                              void* d_out, int out_size, void* d_ws, size_t ws_size,
                              hipStream_t stream) {
    const float* z  = (const float*)d_in[0];   // 16*256*32*32
    const float* cb = (const float*)d_in[1];   // 2048*256
    float* pscore = (float*)d_ws;                       // 4*16384
    int*   pidx   = (int*)(pscore + SPLIT * NPIX);      // 4*16384
    float* An     = (float*)(pidx + SPLIT * NPIX);      // 16384
    float* Bn     = An + NPIX;                          // 2048
    float* ct     = Bn + K_;                            // 256*2048 (2 MB)
    float* out    = (float*)d_out;

    prep_k<<<dim3(200), dim3(256), 0, stream>>>(z, cb, ct, An, Bn);
    vq_k<<<dim3(256 * SPLIT), dim3(256), 0, stream>>>(z, ct, An, Bn, pscore, pidx);
    fin_k<<<dim3(256), dim3(256), 0, stream>>>(cb, pscore, pidx, out);
}

// Round 6
// 281.291 us; speedup vs baseline: 2.8904x; 1.0497x over previous
//
#include <hip/hip_runtime.h>
#include <stdint.h>

// VQ argmin, bit-replicating numpy fp32 reference (see R2).
// R12: LDS-issue reduction. R11 showed VALU busy TIME unchanged vs R8
// (148 vs 153us) -> pk_fma is FLOP-neutral (4cyc/wave); 157.3TF fp32 peak
// is the scalar v_fma rate. Real bottleneck: 4 ds_read_b128/wave/dim-iter
// x 512 iters x 4096 waves / 256 LDS pipes x ~12cyc = 164us LDS-pipe time
// vs 109us VALU-FMA -> LDS-issue-bound (explains wave-count-invariant
// ~62-70% VALUBusy across R6/R8/R9/R11). Fix: jt 8->16 codes/thread
// (NT=KS=512, single chunk, single flush): dim-iters halve -> total b128
// -25% (1536/thread), z-traffic halves, phase loop 32->16, flush 2->1.
// 16 codes = two 8-code groups at tn*8 and 256+tn*8 to keep the 2-way
// bank-free read pattern (contiguous-16 would be 4-way conflicted).
// Ascending-k chains per acc preserved -> BIT-EXACT (absmax 1.907349e-06).
// B=16 D=256 H=W=32 -> n=16384 pixels; K=2048 codes.

#define D_    256
#define K_    2048
#define HW_   1024
#define MT    64      // pixels per block
#define KT    16      // dims per phase
#define SPLIT 4
#define KS    (K_ / SPLIT)   // 512 codes per block = one acc chunk
#define CST   512     // c row stride (floats); 2-way banks on read = free
#define BUFSZ (KT * MT + KT * CST)   // 9216 floats per buffer
#define NPH   (D_ / KT)              // 16 phases (each dim staged once)
#define NPIX  16384

typedef float v2f __attribute__((ext_vector_type(2)));

// global -> LDS direct DMA, 16 B per lane, wave-uniform LDS base (CK-style casts)
__device__ __forceinline__ void gload16(const float* g, float* l) {
    auto* gp = reinterpret_cast<const __attribute__((address_space(1))) uint32_t*>(
        reinterpret_cast<uintptr_t>(g));
    auto* lp = reinterpret_cast<__attribute__((address_space(3))) uint32_t*>(
        reinterpret_cast<uintptr_t>(l));
    __builtin_amdgcn_global_load_lds(gp, lp, 16, 0, 0);
}

// numpy pairwise combine of 8 accumulators
__device__ __forceinline__ float pw8(const float r[8]) {
    float t01 = __fadd_rn(r[0], r[1]);
    float t23 = __fadd_rn(r[2], r[3]);
    float L   = __fadd_rn(t01, t23);
    float t45 = __fadd_rn(r[4], r[5]);
    float t67 = __fadd_rn(r[6], r[7]);
    float R   = __fadd_rn(t45, t67);
    return __fadd_rn(L, R);
}

// prep: blocks [0,128) transpose cb->ct; [128,136) Bn; [136,200) An
__global__ __launch_bounds__(256) void prep_k(const float* __restrict__ z,
                                              const float* __restrict__ cb,
                                              float* __restrict__ ct,
                                              float* __restrict__ An,
                                              float* __restrict__ Bn) {
    __shared__ float t[64][65];
    int tid = threadIdx.x;
    int bx  = blockIdx.x;
    if (bx < 128) {
        int k0 = (bx & 31) << 6;
        int d0 = (bx >> 5) << 6;
        #pragma unroll
        for (int it = 0; it < 4; ++it) {
            int u  = (it << 8) + tid;
            int kk = u >> 4;
            int dd = (u & 15) << 2;
            float4 v = *reinterpret_cast<const float4*>(
                cb + (size_t)(k0 + kk) * D_ + d0 + dd);
            t[kk][dd + 0] = v.x; t[kk][dd + 1] = v.y;
            t[kk][dd + 2] = v.z; t[kk][dd + 3] = v.w;
        }
        __syncthreads();
        #pragma unroll
        for (int it = 0; it < 4; ++it) {
            int u  = (it << 8) + tid;
            int dd = u >> 4;
            int kk = (u & 15) << 2;
            float4 o;
            o.x = t[kk + 0][dd]; o.y = t[kk + 1][dd];
            o.z = t[kk + 2][dd]; o.w = t[kk + 3][dd];
            *reinterpret_cast<float4*>(ct + (size_t)(d0 + dd) * K_ + k0 + kk) = o;
        }
    } else if (bx < 136) {
        int row = (bx - 128) * 256 + tid;
        const float4* p = reinterpret_cast<const float4*>(cb + (size_t)row * D_);
        float rA[8], rB[8];
        #pragma unroll
        for (int j = 0; j < 8; ++j) { rA[j] = 0.f; rB[j] = 0.f; }
        #pragma unroll
        for (int q = 0; q < 64; ++q) {
            float4 v = p[q];
            float pv[4] = {__fmul_rn(v.x, v.x), __fmul_rn(v.y, v.y),
                           __fmul_rn(v.z, v.z), __fmul_rn(v.w, v.w)};
            if (q < 32) {
                #pragma unroll
                for (int l = 0; l < 4; ++l)
                    rA[(4 * q + l) & 7] = __fadd_rn(rA[(4 * q + l) & 7], pv[l]);
            } else {
                #pragma unroll
                for (int l = 0; l < 4; ++l)
                    rB[(4 * q + l) & 7] = __fadd_rn(rB[(4 * q + l) & 7], pv[l]);
            }
        }
        Bn[row] = __fadd_rn(pw8(rA), pw8(rB));
    } else {
        int blk = bx - 136;                  // [0,64): 256 pixels each
        int b   = blk >> 2;
        int hw0 = (blk & 3) << 8;
        const float* zb = z + (size_t)b * (D_ * HW_) + hw0 + tid;
        float rA[8], rB[8];
        #pragma unroll
        for (int j = 0; j < 8; ++j) { rA[j] = 0.f; rB[j] = 0.f; }
        #pragma unroll 8
        for (int d = 0; d < 128; ++d) {      // coalesced: consecutive threads
            float v = zb[(size_t)d * HW_];
            rA[d & 7] = __fadd_rn(rA[d & 7], __fmul_rn(v, v));
        }
        #pragma unroll 8
        for (int d = 128; d < 256; ++d) {
            float v = zb[(size_t)d * HW_];
            rB[d & 7] = __fadd_rn(rB[d & 7], __fmul_rn(v, v));
        }
        An[(size_t)b * HW_ + hw0 + tid] = __fadd_rn(pw8(rA), pw8(rB));
    }
}

// main GEMM+argmin: LDS double-buffered via global_load_lds DMA, pk_fma math
__global__ __launch_bounds__(256, 2) void vq_k(const float* __restrict__ z,
                                               const float* __restrict__ ct,
                                               const float* __restrict__ An,
                                               const float* __restrict__ Bn,
                                               float* __restrict__ pscore,
                                               int* __restrict__ pidx) {
    __shared__ float smem[2 * BUFSZ];            // 73728 B -> 2 blocks/CU
    float* rs = smem;                            // aliased for reduce
    int*   ri = (int*)(smem + MT * 33);

    const int tid  = threadIdx.x;
    const int lane = tid & 63;
    const int w    = tid >> 6;                   // wave id [0,4)
    const int tn   = (tid & 7) | (w << 3);       // [0,32) code-group
    const int tm   = (tid >> 3) & 7;             // [0,8)  pixel-group
    const int blk  = blockIdx.x;
    const int p    = blk / SPLIT;                // pixel-block [0,256)
    const int s    = blk % SPLIT;                // K-split slice
    const int b      = p >> 4;
    const int hwbase = (p & 15) << 6;
    const float* zbase = z + (size_t)b * (D_ * HW_) + hwbase;
    const float* ctS   = ct + s * KS;

    // per-lane DMA source bases (z: lane covers row 4w+(lane>>4), col (lane&15)*4)
    const float* zsrc = zbase + (size_t)((w << 2) + (lane >> 4)) * HW_
                              + ((lane & 15) << 2);

    float bs[8]; int bi[8];
    #pragma unroll
    for (int i = 0; i < 8; ++i) { bs[i] = 1e30f; bi[i] = 0; }
    // acc[i][q]: q<4 -> codes tn*8+{2q,2q+1}; q>=4 -> codes 256+tn*8+{2(q-4),...}
    v2f acc[8][8];
    #pragma unroll
    for (int i = 0; i < 8; ++i)
        #pragma unroll
        for (int q = 0; q < 8; ++q) acc[i][q] = (v2f){0.f, 0.f};

    // stage phase ph into buf[ph&1]: 1 z-DMA + 8 c-DMAs per wave
    #define STAGE(ph)                                                         \
        do {                                                                  \
            int buf_ = (ph) & 1, kc_ = (ph);                                  \
            float* zb_ = smem + buf_ * BUFSZ;                                 \
            float* cb_ = zb_ + KT * MT;                                       \
            gload16(zsrc + (size_t)kc_ * (KT * HW_), zb_ + (w << 2) * MT);    \
            _Pragma("unroll")                                                 \
            for (int r = 0; r < 4; ++r) {                                     \
                int row = (w << 2) + r;                                       \
                const float* src_ = ctS + (size_t)((kc_ << 4) + row) * K_     \
                                        + (lane << 2);                        \
                gload16(src_,       cb_ + row * CST);                         \
                gload16(src_ + 256, cb_ + row * CST + 256);                   \
            }                                                                 \
        } while (0)

    STAGE(0);

    for (int ph = 0; ph < NPH; ++ph) {
        __syncthreads();          // drains phase-ph DMA (issued 1 phase ago)
        if (ph < NPH - 1) STAGE(ph + 1);  // into other buffer (safe: read at ph-1)
        const float* zb_ = smem + (ph & 1) * BUFSZ;
        const float* cb_ = zb_ + KT * MT;
        // ascending-k per-accumulator fma chains — bit-match sgemm
        #pragma unroll
        for (int d = 0; d < KT; ++d) {
            const float* zr = zb_ + d * MT + (tm << 3);
            float4 a0 = *reinterpret_cast<const float4*>(zr);
            float4 a1 = *reinterpret_cast<const float4*>(zr + 4);
            const float* cr = cb_ + d * CST + (tn << 3);
            float4 b0 = *reinterpret_cast<const float4*>(cr);
            float4 b1 = *reinterpret_cast<const float4*>(cr + 4);
            float4 b2 = *reinterpret_cast<const float4*>(cr + 256);
            float4 b3 = *reinterpret_cast<const float4*>(cr + 260);
            v2f bp0 = {b0.x, b0.y}, bp1 = {b0.z, b0.w};
            v2f bp2 = {b1.x, b1.y}, bp3 = {b1.z, b1.w};
            v2f bp4 = {b2.x, b2.y}, bp5 = {b2.z, b2.w};
            v2f bp6 = {b3.x, b3.y}, bp7 = {b3.z, b3.w};
            float az[8] = {a0.x, a0.y, a0.z, a0.w, a1.x, a1.y, a1.z, a1.w};
            #pragma unroll
            for (int i = 0; i < 8; ++i) {
                v2f ai = {az[i], az[i]};
                acc[i][0] = __builtin_elementwise_fma(ai, bp0, acc[i][0]);
                acc[i][1] = __builtin_elementwise_fma(ai, bp1, acc[i][1]);
                acc[i][2] = __builtin_elementwise_fma(ai, bp2, acc[i][2]);
                acc[i][3] = __builtin_elementwise_fma(ai, bp3, acc[i][3]);
                acc[i][4] = __builtin_elementwise_fma(ai, bp4, acc[i][4]);
                acc[i][5] = __builtin_elementwise_fma(ai, bp5, acc[i][5]);
                acc[i][6] = __builtin_elementwise_fma(ai, bp6, acc[i][6]);
                acc[i][7] = __builtin_elementwise_fma(ai, bp7, acc[i][7]);
            }
        }
    }
    #undef STAGE

    // single argmin flush over all 512 codes (ascending ng per thread)
    #pragma unroll
    for (int h = 0; h < 2; ++h) {
        #pragma unroll
        for (int jj = 0; jj < 8; ++jj) {
            int q  = (h << 2) + (jj >> 1);
            int ng = s * KS + h * 256 + (tn << 3) + jj;
            float bn = Bn[ng];
            #pragma unroll
            for (int i = 0; i < 8; ++i) {
                float an = An[(size_t)b * HW_ + hwbase + (tm << 3) + i];
                float sc = __fsub_rn(__fadd_rn(an, bn),
                                     __fmul_rn(2.0f, acc[i][q][jj & 1]));
                if (sc < bs[i]) { bs[i] = sc; bi[i] = ng; }
            }
        }
    }

    __syncthreads();   // protect smem before aliasing
    #pragma unroll
    for (int i = 0; i < 8; ++i) {
        int m = (tm << 3) + i;
        rs[m * 33 + tn] = bs[i];
        ri[m * 33 + tn] = bi[i];
    }
    __syncthreads();
    if (tid < MT) {
        int   m    = tid;
        float best = rs[m * 33];
        int   bidx = ri[m * 33];
        for (int t = 1; t < 32; ++t) {
            float sv = rs[m * 33 + t];
            int   ix = ri[m * 33 + t];
            if (sv < best || (sv == best && ix < bidx)) { best = sv; bidx = ix; }
        }
        int g = b * HW_ + hwbase + m;
        pscore[s * NPIX + g] = best;
        pidx[s * NPIX + g]   = bidx;
    }
}

// merge SPLIT partials (first-min tiebreak) + gather output
__global__ __launch_bounds__(256) void fin_k(const float* __restrict__ cb,
                                             const float* __restrict__ pscore,
                                             const int* __restrict__ pidx,
                                             float* __restrict__ out) {
    __shared__ int idxs[MT];
    int tid = threadIdx.x;
    int p   = blockIdx.x;               // [0,256)
    int b      = p >> 4;
    int hwbase = (p & 15) << 6;
    if (tid < MT) {
        int g = b * HW_ + hwbase + tid;
        float best = pscore[g];
        int   bidx = pidx[g];
        #pragma unroll
        for (int s = 1; s < SPLIT; ++s) {
            float sv = pscore[s * NPIX + g];
            int   ix = pidx[s * NPIX + g];
            if (sv < best || (sv == best && ix < bidx)) { best = sv; bidx = ix; }
        }
        idxs[tid] = bidx;
    }
    __syncthreads();
    float* obase = out + (size_t)b * (D_ * HW_) + hwbase;
    #pragma unroll
    for (int it = 0; it < 16; ++it) {
        int u  = (it << 8) + tid;
        int dd = u >> 4;                // [0,256)
        int m4 = u & 15;
        int i0 = idxs[(m4 << 2) + 0];
        int i1 = idxs[(m4 << 2) + 1];
        int i2 = idxs[(m4 << 2) + 2];
        int i3 = idxs[(m4 << 2) + 3];
        float4 o;
        o.x = cb[(size_t)i0 * D_ + dd];
        o.y = cb[(size_t)i1 * D_ + dd];
        o.z = cb[(size_t)i2 * D_ + dd];
        o.w = cb[(size_t)i3 * D_ + dd];
        *reinterpret_cast<float4*>(obase + (size_t)dd * HW_ + (m4 << 2)) = o;
    }
}

extern "C" void kernel_launch(void* const* d_in, const int* in_sizes, int n_in,
                              void* d_out, int out_size, void* d_ws, size_t ws_size,
                              hipStream_t stream) {
    const float* z  = (const float*)d_in[0];   // 16*256*32*32
    const float* cb = (const float*)d_in[1];   // 2048*256
    float* pscore = (float*)d_ws;                       // 4*16384
    int*   pidx   = (int*)(pscore + SPLIT * NPIX);      // 4*16384
    float* An     = (float*)(pidx + SPLIT * NPIX);      // 16384
    float* Bn     = An + NPIX;                          // 2048
    float* ct     = Bn + K_;                            // 256*2048 (2 MB)
    float* out    = (float*)d_out;

    prep_k<<<dim3(200), dim3(256), 0, stream>>>(z, cb, ct, An, Bn);
    vq_k<<<dim3(256 * SPLIT), dim3(256), 0, stream>>>(z, ct, An, Bn, pscore, pidx);
    fin_k<<<dim3(256), dim3(256), 0, stream>>>(cb, pscore, pidx, out);
}